// Round 17
// baseline (304.622 us; speedup 1.0000x reference)
//
#include <hip/hip_runtime.h>
#include <stdint.h>

#define N_NODES 50000
#define N_EDGES 800000
#define DIM     128
#define TOT     (N_NODES * DIM)   // 6,400,000
#define NB   196                 // dst buckets: dst>>8
#define CAP  8192                // fixed slots per bucket in 'packed' (mean 4096, sigma 64)
#define CHUNK 8192               // edges per scatter block
#define NBLK 98                  // ceil(800000/8192)
#define GCAP 4096                // LDS edge cap for gather blocks (mean 1024 @64 nodes)
#define G3CAP 8192               // LDS edge cap for gather3 blocks (mean 4096)
#define XBLKS (TOT / 4 / 256)    // 6250

typedef __attribute__((ext_vector_type(8))) unsigned short ushort8_t;
typedef __attribute__((ext_vector_type(8))) short bfrag;    // 8 bf16 = 4 VGPR
typedef __attribute__((ext_vector_type(4))) float f32x4;

// ---------------- Threefry-2x32 (exact JAX 20-round) ----------------
__host__ __device__ inline void threefry2x32(uint32_t k0, uint32_t k1,
                                             uint32_t x0, uint32_t x1,
                                             uint32_t& o0, uint32_t& o1) {
    uint32_t ks0 = k0, ks1 = k1, ks2 = k0 ^ k1 ^ 0x1BD11BDAu;
    uint32_t v0 = x0 + ks0, v1 = x1 + ks1;
#define TF_R(r) { v0 += v1; v1 = (v1 << (r)) | (v1 >> (32 - (r))); v1 ^= v0; }
    TF_R(13) TF_R(15) TF_R(26) TF_R(6)
    v0 += ks1; v1 += ks2 + 1u;
    TF_R(17) TF_R(29) TF_R(16) TF_R(24)
    v0 += ks2; v1 += ks0 + 2u;
    TF_R(13) TF_R(15) TF_R(26) TF_R(6)
    v0 += ks0; v1 += ks1 + 3u;
    TF_R(17) TF_R(29) TF_R(16) TF_R(24)
    v0 += ks1; v1 += ks2 + 4u;
    TF_R(13) TF_R(15) TF_R(26) TF_R(6)
    v0 += ks2; v1 += ks0 + 5u;
#undef TF_R
    o0 = v0; o1 = v1;
}

__device__ inline float drop_scale(uint32_t kk0, uint32_t kk1, uint32_t i) {
    uint32_t b0, b1;
    threefry2x32(kk0, kk1, 0u, i, b0, b1);
    uint32_t bits = b0 ^ b1;               // partitionable 32-bit path (verified R0)
    return (bits >> 31) ? 0.0f : 2.0f;     // keep iff u < 0.5 iff top bit 0
}

__device__ inline float bf2f(ushort u) {
    return __uint_as_float(((uint32_t)u) << 16);
}
__device__ inline float bfpair_lo(uint32_t u) { return __uint_as_float(u << 16); }
__device__ inline float bfpair_hi(uint32_t u) { return __uint_as_float(u & 0xffff0000u); }

__device__ inline ushort f2bf_rne(float f) {
    uint32_t bits = __float_as_uint(f);
    uint32_t lsb = (bits >> 16) & 1u;
    bits += 0x7fffu + lsb;                 // round-to-nearest-even
    return (ushort)(bits >> 16);
}

// ---------------- MFMA GEMM body: H = X @ W, scaled bf16, 32-feat-pair out ---
// Hb[fp][v][32], fp in [0,4). [m89/m91 verified mapping; passed R11]
__device__ inline void gemm_body(const ushort* __restrict__ Xb,
                                 const ushort* __restrict__ Wt,
                                 const float* __restrict__ dis,
                                 ushort* __restrict__ Hb, int gb, int tid) {
    int w = tid >> 6, lane = tid & 63;
    int m0 = gb * 128 + w * 32;
    int lrow = lane & 15, quad = lane >> 4;
    f32x4 acc[2][8] = {};
    for (int kt = 0; kt < DIM; kt += 32) {
        bfrag a[2], b[8];
        #pragma unroll
        for (int t = 0; t < 2; ++t) {
            int m = m0 + t * 16 + lrow;
            if (m >= N_NODES) m = 0;
            a[t] = *(const bfrag*)(Xb + (size_t)m * DIM + kt + quad * 8);
        }
        #pragma unroll
        for (int c = 0; c < 8; ++c) {
            int n = c * 16 + lrow;
            b[c] = *(const bfrag*)(Wt + (size_t)n * DIM + kt + quad * 8);
        }
        #pragma unroll
        for (int t = 0; t < 2; ++t)
            #pragma unroll
            for (int c = 0; c < 8; ++c)
                acc[t][c] = __builtin_amdgcn_mfma_f32_16x16x32_bf16(a[t], b[c], acc[t][c], 0, 0, 0);
    }
    #pragma unroll
    for (int t = 0; t < 2; ++t) {
        #pragma unroll
        for (int r = 0; r < 4; ++r) {
            int rowi = m0 + t * 16 + quad * 4 + r;
            if (rowi < N_NODES) {
                float dv = dis[rowi];
                #pragma unroll
                for (int c = 0; c < 8; ++c) {
                    int feat = c * 16 + lrow;
                    int fp = feat >> 5, off = feat & 31;
                    Hb[((size_t)fp * N_NODES + rowi) * 32 + off] = f2bf_rne(acc[t][c][r] * dv);
                }
            }
        }
    }
}

// ---- launch A: x->bf16 | W transpose | scatter (LDS hist + atomic reserve + deg)
__global__ __launch_bounds__(256) void k_prep(const float* __restrict__ x,
                                              const float* __restrict__ W1,
                                              const float* __restrict__ W2,
                                              ushort* __restrict__ Xb,
                                              ushort* __restrict__ W1t,
                                              ushort* __restrict__ W2t,
                                              const int* __restrict__ src,
                                              const int* __restrict__ dst,
                                              uint32_t* __restrict__ gcur,
                                              uint32_t* __restrict__ deg,
                                              uint32_t* __restrict__ packed) {
    __shared__ uint32_t h[NB];
    int b = blockIdx.x;
    int t = threadIdx.x;
    if (b < XBLKS) {
        int i = b * 256 + t;
        float4 v = ((const float4*)x)[i];
        ushort4 o;
        o.x = f2bf_rne(v.x); o.y = f2bf_rne(v.y);
        o.z = f2bf_rne(v.z); o.w = f2bf_rne(v.w);
        ((ushort4*)Xb)[i] = o;
    } else if (b < XBLKS + 128) {
        int j = (b - XBLKS) * 256 + t;             // 0..32767
        const float* W = (j < DIM * DIM) ? W1 : W2;
        ushort* Wt = (j < DIM * DIM) ? W1t : W2t;
        int i = j & (DIM * DIM - 1);
        int k = i >> 7, n = i & 127;
        Wt[n * DIM + k] = f2bf_rne(W[k * DIM + n]);
    } else {
        int sb = b - XBLKS - 128;                  // 0..NBLK-1
        if (t < NB) h[t] = 0u;
        __syncthreads();
        int base = sb * CHUNK;
        #pragma unroll
        for (int i = 0; i < CHUNK / 256; ++i) {
            int e = base + i * 256 + t;
            if (e < N_EDGES) atomicAdd(&h[((uint32_t)dst[e]) >> 8], 1u);
        }
        __syncthreads();
        if (t < NB) {
            uint32_t c = h[t];
            h[t] = c ? atomicAdd(&gcur[t], c) : 0u;   // reserve contiguous run
        }
        __syncthreads();
        #pragma unroll
        for (int i = 0; i < CHUNK / 256; ++i) {
            int e = base + i * 256 + t;
            if (e < N_EDGES) {
                uint32_t d = (uint32_t)dst[e];
                uint32_t s = (uint32_t)src[e];
                uint32_t bk = d >> 8;
                uint32_t pos = atomicAdd(&h[bk], 1u);
                if (pos < CAP)
                    packed[(size_t)bk * CAP + pos] = ((d & 255u) << 16) | s;
                atomicAdd(&deg[d], 1u);             // degree for dis
            }
        }
    }
}

__global__ void k_dis(const uint32_t* __restrict__ deg, float* __restrict__ dis) {
    int v = blockIdx.x * 256 + threadIdx.x;
    if (v < N_NODES) dis[v] = 1.0f / sqrtf((float)(deg[v] + 1u));
}

// ---- launch B: per-bucket CSR fill -> COMPACT space (blocks 0..NB) | L1 GEMM --
// R16 bug fix: padded row[] made the last node of each bucket walk into the
// pad garbage. Fill now reduces gcur[0..b) in LDS for a compact base; row and
// col16 live in contiguous compact space (row[50000]=800000).
__global__ __launch_bounds__(256) void k_fill_gemm(const uint32_t* __restrict__ gcur,
                                                   const uint32_t* __restrict__ packed,
                                                   uint32_t* __restrict__ row,
                                                   float* __restrict__ dis,
                                                   ushort* __restrict__ col16,
                                                   const ushort* __restrict__ Xb,
                                                   const ushort* __restrict__ W1t,
                                                   ushort* __restrict__ Hb) {
    __shared__ uint32_t sdeg[256];
    __shared__ uint32_t scan[256];
    __shared__ uint32_t cur[256];
    int b = blockIdx.x;
    int t = threadIdx.x;
    if (b >= NB) {
        gemm_body(Xb, W1t, dis, Hb, b - NB, t);    // dis valid: k_dis ran before
        return;
    }
    uint32_t n = gcur[b];
    // compact base = sum gcur[0..b) via inclusive scan of masked values
    scan[t] = (t < b) ? gcur[t] : 0u;              // b <= 195 < 256
    __syncthreads();
    for (int off = 1; off < 256; off <<= 1) {
        uint32_t x = (t >= off) ? scan[t - off] : 0u;
        __syncthreads();
        scan[t] += x;
        __syncthreads();
    }
    uint32_t cbase = scan[255];
    __syncthreads();
    uint32_t pbase = (uint32_t)b * CAP;
    sdeg[t] = 0u;
    __syncthreads();
    uint32_t mine[24]; int cnt = 0;
    for (uint32_t i = t; i < n; i += 256) {
        uint32_t u = packed[pbase + i];
        mine[cnt++] = u;
        atomicAdd(&sdeg[u >> 16], 1u);
    }
    __syncthreads();
    uint32_t myd = sdeg[t];
    scan[t] = myd;
    __syncthreads();
    for (int off = 1; off < 256; off <<= 1) {
        uint32_t x = (t >= off) ? scan[t - off] : 0u;
        __syncthreads();
        scan[t] += x;
        __syncthreads();
    }
    uint32_t excl = scan[t] - myd;
    cur[t] = excl;
    int v = b * 256 + t;
    if (v <= N_NODES) row[v] = cbase + excl;       // compact offsets; row[50000]=800000
    if (v < N_NODES)  dis[v] = 1.0f / sqrtf((float)(myd + 1u));  // same bits as k_dis
    __syncthreads();
    for (int j = 0; j < cnt; ++j) {
        uint32_t u = mine[j];
        uint32_t pos = cbase + atomicAdd(&cur[u >> 16], 1u);
        col16[pos] = (ushort)(u & 0xffffu);
    }
}

// ---------------- fused gather + bias + leaky + dropout ----------------
// Block (fp = blockIdx&3 -> 32-feat pair, c): 64 nodes; thread=(node, 8-feat q).
// 4 adjacent lanes read one 64B line per edge; line-complete 16B stores (R14).
__global__ __launch_bounds__(256) void k_gather(const uint32_t* __restrict__ row,
                                                const ushort* __restrict__ col16,
                                                const float* __restrict__ dis,
                                                const ushort* __restrict__ Hb,
                                                const float* __restrict__ bias,
                                                ushort* __restrict__ OUTb,
                                                uint32_t kk0, uint32_t kk1) {
    __shared__ ushort scol[GCAP];
    __shared__ uint32_t srow[65];
    int fp = blockIdx.x & 3;
    int c = blockIdx.x >> 2;
    int tid = threadIdx.x;
    int nbase = c * 64;
    int nend = nbase + 64; if (nend > N_NODES) nend = N_NODES;
    int nloc = nend - nbase;
    for (int i = tid; i <= nloc; i += 256) srow[i] = row[nbase + i];
    __syncthreads();
    uint32_t eLo = srow[0];
    uint32_t count = srow[nloc] - eLo;
    bool staged = count <= GCAP;
    if (staged) {
        for (uint32_t i = tid; i < count; i += 256) scol[i] = col16[eLo + i];
    }
    __syncthreads();

    int nl = tid >> 2;                 // node in block
    int q  = tid & 3;                  // 8-feat quarter of the 32-feat pair
    int v = nbase + nl;
    if (v >= N_NODES) return;
    const ushort* Hf = Hb + (size_t)fp * N_NODES * 32;
    ushort8_t hv = *((const ushort8_t*)(Hf + (size_t)v * 32 + q * 8));
    float acc[8];
    #pragma unroll
    for (int j = 0; j < 8; ++j) acc[j] = bf2f(hv[j]);

    uint32_t e0 = srow[nl] - eLo, e1 = srow[nl + 1] - eLo;
    uint32_t e = e0;
    if (staged) {
        for (; e + 4 <= e1; e += 4) {
            uint32_t s0 = scol[e], s1 = scol[e + 1], s2 = scol[e + 2], s3 = scol[e + 3];
            ushort8_t h0 = *((const ushort8_t*)(Hf + (size_t)s0 * 32 + q * 8));
            ushort8_t h1 = *((const ushort8_t*)(Hf + (size_t)s1 * 32 + q * 8));
            ushort8_t h2 = *((const ushort8_t*)(Hf + (size_t)s2 * 32 + q * 8));
            ushort8_t h3 = *((const ushort8_t*)(Hf + (size_t)s3 * 32 + q * 8));
            #pragma unroll
            for (int j = 0; j < 8; ++j)
                acc[j] += (bf2f(h0[j]) + bf2f(h1[j])) + (bf2f(h2[j]) + bf2f(h3[j]));
        }
        for (; e < e1; ++e) {
            uint32_t s0 = scol[e];
            ushort8_t h0 = *((const ushort8_t*)(Hf + (size_t)s0 * 32 + q * 8));
            #pragma unroll
            for (int j = 0; j < 8; ++j) acc[j] += bf2f(h0[j]);
        }
    } else {
        for (; e < e1; ++e) {
            uint32_t s0 = col16[eLo + e];
            ushort8_t h0 = *((const ushort8_t*)(Hf + (size_t)s0 * 32 + q * 8));
            #pragma unroll
            for (int j = 0; j < 8; ++j) acc[j] += bf2f(h0[j]);
        }
    }

    float dv = dis[v];
    int cbase = fp * 32 + q * 8;
    uint32_t ibase = (uint32_t)(v * DIM + cbase);
    ushort8_t o;
    #pragma unroll
    for (int j = 0; j < 8; ++j) {
        float z = acc[j] * dv + bias[cbase + j];
        z = (z >= 0.f) ? z : 0.01f * z;
        z *= drop_scale(kk0, kk1, ibase + j);
        o[j] = f2bf_rne(z);
    }
    *((ushort8_t*)(OUTb + (size_t)v * DIM + cbase)) = o;
}

// ---------------- standalone layer-2 MFMA GEMM ----------------
__global__ __launch_bounds__(256) void k_gemm_mfma(const ushort* __restrict__ Xb,
                                                   const ushort* __restrict__ Wt,
                                                   const float* __restrict__ dis,
                                                   ushort* __restrict__ Hb) {
    gemm_body(Xb, Wt, dis, Hb, blockIdx.x, threadIdx.x);
}

// ---------------- classifier GEMM: (N x 128 bf16) @ (128 x 2 fp32), scaled ----
__global__ void k_gemm_cls(const ushort* __restrict__ Bb, const float* __restrict__ W3,
                           const float* __restrict__ dis, float* __restrict__ O) {
    int v = blockIdx.x * blockDim.x + threadIdx.x;
    if (v >= N_NODES) return;
    const uint32_t* r = (const uint32_t*)(Bb + (size_t)v * DIM);
    float a0 = 0.f, a1 = 0.f;
#pragma unroll 8
    for (int w = 0; w < 64; ++w) {
        uint32_t u = r[w];
        float x0 = bfpair_lo(u), x1 = bfpair_hi(u);
        const float* wp = W3 + w * 4;
        a0 += x0 * wp[0] + x1 * wp[2];
        a1 += x0 * wp[1] + x1 * wp[3];
    }
    float dv = dis[v];
    O[v * 2 + 0] = a0 * dv;
    O[v * 2 + 1] = a1 * dv;
}

// ---------------- fused layer-3 gather + bias + log_softmax, LDS-staged ------
__global__ __launch_bounds__(256) void k_gather3(const uint32_t* __restrict__ row,
                                                 const ushort* __restrict__ col16,
                                                 const float* __restrict__ dis,
                                                 const float* __restrict__ H3s,
                                                 const float* __restrict__ b3,
                                                 float* __restrict__ out) {
    __shared__ ushort scol[G3CAP];
    __shared__ uint32_t srow[257];
    int tid = threadIdx.x;
    int nbase = blockIdx.x * 256;
    int nend = nbase + 256; if (nend > N_NODES) nend = N_NODES;
    int nloc = nend - nbase;
    for (int i = tid; i <= nloc; i += 256) srow[i] = row[nbase + i];
    __syncthreads();
    uint32_t eLo = srow[0];
    uint32_t count = srow[nloc] - eLo;
    bool staged = count <= G3CAP;
    if (staged) {
        for (uint32_t i = tid; i < count; i += 256) scol[i] = col16[eLo + i];
    }
    __syncthreads();

    int v = nbase + tid;
    if (v >= N_NODES) return;
    const float2* H2 = (const float2*)H3s;
    float2 h = H2[v];
    float z0 = h.x, z1 = h.y;
    uint32_t e0 = srow[tid] - eLo, e1 = srow[tid + 1] - eLo;
    uint32_t e = e0;
    if (staged) {
        for (; e + 2 <= e1; e += 2) {
            float2 ha = H2[scol[e]];
            float2 hb = H2[scol[e + 1]];
            z0 += ha.x + hb.x; z1 += ha.y + hb.y;
        }
        if (e < e1) {
            float2 ha = H2[scol[e]];
            z0 += ha.x; z1 += ha.y;
        }
    } else {
        for (; e < e1; ++e) {
            float2 ha = H2[col16[eLo + e]];
            z0 += ha.x; z1 += ha.y;
        }
    }
    float dv = dis[v];
    z0 = z0 * dv + b3[0];
    z1 = z1 * dv + b3[1];
    float m = fmaxf(z0, z1);
    float lse = m + logf(expf(z0 - m) + expf(z1 - m));
    out[v * 2 + 0] = z0 - lse;
    out[v * 2 + 1] = z1 - lse;
}

extern "C" void kernel_launch(void* const* d_in, const int* in_sizes, int n_in,
                              void* d_out, int out_size, void* d_ws, size_t ws_size,
                              hipStream_t stream) {
    const float* x  = (const float*)d_in[0];
    const int*   ei = (const int*)d_in[1];
    const float* W1 = (const float*)d_in[2];
    const float* b1 = (const float*)d_in[3];
    const float* W2 = (const float*)d_in[4];
    const float* b2 = (const float*)d_in[5];
    const float* W3 = (const float*)d_in[6];
    const float* b3 = (const float*)d_in[7];
    float* out = (float*)d_out;

    const int* src = ei;
    const int* dst = ei + N_EDGES;

    // workspace layout (u32 units) -- all regions disjoint (R10 lesson)
    uint32_t* wsu = (uint32_t*)d_ws;
    float*    wsf = (float*)d_ws;
    uint32_t* gcur   = wsu;                       // [0, 196) -> pad 256
    uint32_t* deg    = wsu + 256;                 // [256, 50256) -> pad 50304
    uint32_t* row    = wsu + 50304;               // [50304, 100305) -> pad 100352
    float*    dis    = wsf + 100352;              // [100352, 150352) -> pad 150400
    uint32_t* packed = wsu + 150400;              // 196*8192 -> [150400, 1756032)
    ushort*   col16  = (ushort*)(wsu + 1756032);  // 800000 u16 -> [1756032, 2156032); pad to 2158848
    ushort*   Hb     = (ushort*)(wsu + 2158848);  // [2158848, 5358848)
    ushort*   Xb     = (ushort*)(wsu + 5358848);  // [5358848, 8558848)
    ushort*   Bb     = (ushort*)(wsu + 8558848);  // [8558848, 11758848)
    ushort*   W1t    = (ushort*)(wsu + 11758848); // [11758848, 11767040)
    ushort*   W2t    = (ushort*)(wsu + 11767040); // [11767040, 11775232)
    float*    h3s    = wsf + 11775232;            // [11775232, 11875232)

    // dropout keys: threefry-partitionable fold-like split of key(42) (verified R0)
    uint32_t k1a, k1b, k2a, k2b;
    threefry2x32(0u, 42u, 0u, 0u, k1a, k1b);
    threefry2x32(0u, 42u, 0u, 1u, k2a, k2b);

    hipMemsetAsync(gcur, 0, 256 * sizeof(uint32_t), stream);
    hipMemsetAsync(deg, 0, N_NODES * sizeof(uint32_t), stream);

    // ---- A: converts | scatter (hist + reserve + degree) ----
    k_prep<<<XBLKS + 128 + NBLK, 256, 0, stream>>>(x, W1, W2, Xb, W1t, W2t,
                                                   src, dst, gcur, deg, packed);
    k_dis<<<(N_NODES + 255) / 256, 256, 0, stream>>>(deg, dis);

    int mgrid = (N_NODES + 127) / 128;                   // 391
    int ggrid = ((N_NODES + 63) / 64) * 4;               // (fp, 64-node chunk)

    // ---- B: CSR fill (compact) | layer-1 GEMM (one launch) ----
    k_fill_gemm<<<NB + mgrid, 256, 0, stream>>>(gcur, packed, row, dis, col16,
                                                Xb, W1t, Hb);

    // ---- layer 1 gather ----
    k_gather<<<ggrid, 256, 0, stream>>>(row, col16, dis, Hb, b1, Bb, k1a, k1b);

    // ---- layer 2 ----
    k_gemm_mfma<<<mgrid, 256, 0, stream>>>(Bb, W2t, dis, Hb);
    k_gather<<<ggrid, 256, 0, stream>>>(row, col16, dis, Hb, b2, Bb, k2a, k2b);

    // ---- layer 3 ----
    k_gemm_cls<<<(N_NODES + 255) / 256, 256, 0, stream>>>(Bb, W3, dis, h3s);
    k_gather3<<<(N_NODES + 255) / 256, 256, 0, stream>>>(row, col16, dis, h3s, b3, out);
}

// Round 18
// 241.489 us; speedup vs baseline: 1.2614x; 1.2614x over previous
//
#include <hip/hip_runtime.h>
#include <stdint.h>

#define N_NODES 50000
#define N_EDGES 800000
#define DIM     128
#define TOT     (N_NODES * DIM)   // 6,400,000
#define NB   196                 // dst buckets: dst>>8
#define CAP  8192                // fixed slots per bucket in 'packed' (mean 4096, sigma 64)
#define CHUNK 2048               // edges per scatter block (391 blocks -> real parallelism)
#define NBLK 391                 // ceil(800000/2048)
#define GCAP 4096                // LDS edge cap for gather blocks (mean 1024 @64 nodes)
#define G3CAP 8192               // LDS edge cap for gather3 blocks (mean 4096)
#define XBLKS (TOT / 4 / 256)    // 6250

typedef __attribute__((ext_vector_type(8))) unsigned short ushort8_t;
typedef __attribute__((ext_vector_type(8))) short bfrag;    // 8 bf16 = 4 VGPR
typedef __attribute__((ext_vector_type(4))) float f32x4;

// ---------------- Threefry-2x32 (exact JAX 20-round) ----------------
__host__ __device__ inline void threefry2x32(uint32_t k0, uint32_t k1,
                                             uint32_t x0, uint32_t x1,
                                             uint32_t& o0, uint32_t& o1) {
    uint32_t ks0 = k0, ks1 = k1, ks2 = k0 ^ k1 ^ 0x1BD11BDAu;
    uint32_t v0 = x0 + ks0, v1 = x1 + ks1;
#define TF_R(r) { v0 += v1; v1 = (v1 << (r)) | (v1 >> (32 - (r))); v1 ^= v0; }
    TF_R(13) TF_R(15) TF_R(26) TF_R(6)
    v0 += ks1; v1 += ks2 + 1u;
    TF_R(17) TF_R(29) TF_R(16) TF_R(24)
    v0 += ks2; v1 += ks0 + 2u;
    TF_R(13) TF_R(15) TF_R(26) TF_R(6)
    v0 += ks0; v1 += ks1 + 3u;
    TF_R(17) TF_R(29) TF_R(16) TF_R(24)
    v0 += ks1; v1 += ks2 + 4u;
    TF_R(13) TF_R(15) TF_R(26) TF_R(6)
    v0 += ks2; v1 += ks0 + 5u;
#undef TF_R
    o0 = v0; o1 = v1;
}

__device__ inline float drop_scale(uint32_t kk0, uint32_t kk1, uint32_t i) {
    uint32_t b0, b1;
    threefry2x32(kk0, kk1, 0u, i, b0, b1);
    uint32_t bits = b0 ^ b1;               // partitionable 32-bit path (verified R0)
    return (bits >> 31) ? 0.0f : 2.0f;     // keep iff u < 0.5 iff top bit 0
}

__device__ inline float bf2f(ushort u) {
    return __uint_as_float(((uint32_t)u) << 16);
}
__device__ inline float bfpair_lo(uint32_t u) { return __uint_as_float(u << 16); }
__device__ inline float bfpair_hi(uint32_t u) { return __uint_as_float(u & 0xffff0000u); }

__device__ inline ushort f2bf_rne(float f) {
    uint32_t bits = __float_as_uint(f);
    uint32_t lsb = (bits >> 16) & 1u;
    bits += 0x7fffu + lsb;                 // round-to-nearest-even
    return (ushort)(bits >> 16);
}

// ---------------- MFMA GEMM body: H = X @ W, scaled bf16, 32-feat-pair out ---
// Hb[fp][v][32], fp in [0,4). [m89/m91 verified mapping; passed R11-R17]
__device__ inline void gemm_body(const ushort* __restrict__ Xb,
                                 const ushort* __restrict__ Wt,
                                 const float* __restrict__ dis,
                                 ushort* __restrict__ Hb, int gb, int tid) {
    int w = tid >> 6, lane = tid & 63;
    int m0 = gb * 128 + w * 32;
    int lrow = lane & 15, quad = lane >> 4;
    f32x4 acc[2][8] = {};
    for (int kt = 0; kt < DIM; kt += 32) {
        bfrag a[2], b[8];
        #pragma unroll
        for (int t = 0; t < 2; ++t) {
            int m = m0 + t * 16 + lrow;
            if (m >= N_NODES) m = 0;
            a[t] = *(const bfrag*)(Xb + (size_t)m * DIM + kt + quad * 8);
        }
        #pragma unroll
        for (int c = 0; c < 8; ++c) {
            int n = c * 16 + lrow;
            b[c] = *(const bfrag*)(Wt + (size_t)n * DIM + kt + quad * 8);
        }
        #pragma unroll
        for (int t = 0; t < 2; ++t)
            #pragma unroll
            for (int c = 0; c < 8; ++c)
                acc[t][c] = __builtin_amdgcn_mfma_f32_16x16x32_bf16(a[t], b[c], acc[t][c], 0, 0, 0);
    }
    #pragma unroll
    for (int t = 0; t < 2; ++t) {
        #pragma unroll
        for (int r = 0; r < 4; ++r) {
            int rowi = m0 + t * 16 + quad * 4 + r;
            if (rowi < N_NODES) {
                float dv = dis[rowi];
                #pragma unroll
                for (int c = 0; c < 8; ++c) {
                    int feat = c * 16 + lrow;
                    int fp = feat >> 5, off = feat & 31;
                    Hb[((size_t)fp * N_NODES + rowi) * 32 + off] = f2bf_rne(acc[t][c][r] * dv);
                }
            }
        }
    }
}

// ---- launch A: x->bf16 | W transpose | scatter (LDS hist + atomic reserve) ---
// NO per-edge deg atomic (R17 lesson: it serialized the 98-block tail); deg
// comes free from k_fill's sdeg. 391 scatter blocks for real parallelism.
__global__ __launch_bounds__(256) void k_prep(const float* __restrict__ x,
                                              const float* __restrict__ W1,
                                              const float* __restrict__ W2,
                                              ushort* __restrict__ Xb,
                                              ushort* __restrict__ W1t,
                                              ushort* __restrict__ W2t,
                                              const int* __restrict__ src,
                                              const int* __restrict__ dst,
                                              uint32_t* __restrict__ gcur,
                                              uint32_t* __restrict__ packed) {
    __shared__ uint32_t h[NB];
    int b = blockIdx.x;
    int t = threadIdx.x;
    if (b < XBLKS) {
        int i = b * 256 + t;
        float4 v = ((const float4*)x)[i];
        ushort4 o;
        o.x = f2bf_rne(v.x); o.y = f2bf_rne(v.y);
        o.z = f2bf_rne(v.z); o.w = f2bf_rne(v.w);
        ((ushort4*)Xb)[i] = o;
    } else if (b < XBLKS + 128) {
        int j = (b - XBLKS) * 256 + t;             // 0..32767
        const float* W = (j < DIM * DIM) ? W1 : W2;
        ushort* Wt = (j < DIM * DIM) ? W1t : W2t;
        int i = j & (DIM * DIM - 1);
        int k = i >> 7, n = i & 127;
        Wt[n * DIM + k] = f2bf_rne(W[k * DIM + n]);
    } else {
        int sb = b - XBLKS - 128;                  // 0..NBLK-1
        if (t < NB) h[t] = 0u;
        __syncthreads();
        int base = sb * CHUNK;
        #pragma unroll
        for (int i = 0; i < CHUNK / 256; ++i) {
            int e = base + i * 256 + t;
            if (e < N_EDGES) atomicAdd(&h[((uint32_t)dst[e]) >> 8], 1u);
        }
        __syncthreads();
        if (t < NB) {
            uint32_t c = h[t];
            h[t] = c ? atomicAdd(&gcur[t], c) : 0u;   // reserve contiguous run
        }
        __syncthreads();
        #pragma unroll
        for (int i = 0; i < CHUNK / 256; ++i) {
            int e = base + i * 256 + t;
            if (e < N_EDGES) {
                uint32_t d = (uint32_t)dst[e];
                uint32_t s = (uint32_t)src[e];
                uint32_t bk = d >> 8;
                uint32_t pos = atomicAdd(&h[bk], 1u);
                if (pos < CAP)
                    packed[(size_t)bk * CAP + pos] = ((d & 255u) << 16) | s;
            }
        }
    }
}

// ---- k_fill: per-bucket CSR -> COMPACT space; also writes row & dis ---------
// Compact base = LDS scan of gcur[0..b) (R16 pad-walk bug fix, verified R17).
__global__ __launch_bounds__(256) void k_fill(const uint32_t* __restrict__ gcur,
                                              const uint32_t* __restrict__ packed,
                                              uint32_t* __restrict__ row,
                                              float* __restrict__ dis,
                                              ushort* __restrict__ col16) {
    __shared__ uint32_t sdeg[256];
    __shared__ uint32_t scan[256];
    __shared__ uint32_t cur[256];
    int b = blockIdx.x;
    int t = threadIdx.x;
    uint32_t n = gcur[b];
    scan[t] = (t < b) ? gcur[t] : 0u;              // b <= 195 < 256
    __syncthreads();
    for (int off = 1; off < 256; off <<= 1) {
        uint32_t x = (t >= off) ? scan[t - off] : 0u;
        __syncthreads();
        scan[t] += x;
        __syncthreads();
    }
    uint32_t cbase = scan[255];
    __syncthreads();
    uint32_t pbase = (uint32_t)b * CAP;
    sdeg[t] = 0u;
    __syncthreads();
    uint32_t mine[24]; int cnt = 0;
    for (uint32_t i = t; i < n; i += 256) {
        uint32_t u = packed[pbase + i];
        mine[cnt++] = u;
        atomicAdd(&sdeg[u >> 16], 1u);
    }
    __syncthreads();
    uint32_t myd = sdeg[t];
    scan[t] = myd;
    __syncthreads();
    for (int off = 1; off < 256; off <<= 1) {
        uint32_t x = (t >= off) ? scan[t - off] : 0u;
        __syncthreads();
        scan[t] += x;
        __syncthreads();
    }
    uint32_t excl = scan[t] - myd;
    cur[t] = excl;
    int v = b * 256 + t;
    if (v <= N_NODES) row[v] = cbase + excl;       // compact; row[50000]=800000
    if (v < N_NODES)  dis[v] = 1.0f / sqrtf((float)(myd + 1u));
    __syncthreads();
    for (int j = 0; j < cnt; ++j) {
        uint32_t u = mine[j];
        uint32_t pos = cbase + atomicAdd(&cur[u >> 16], 1u);
        col16[pos] = (ushort)(u & 0xffffu);
    }
}

// ---------------- fused gather + bias + leaky + dropout ----------------
// Block (fp = blockIdx&3 -> 32-feat pair, c): 64 nodes; thread=(node, 8-feat q).
// 4 adjacent lanes read one 64B line per edge; line-complete 16B stores (R14).
__global__ __launch_bounds__(256) void k_gather(const uint32_t* __restrict__ row,
                                                const ushort* __restrict__ col16,
                                                const float* __restrict__ dis,
                                                const ushort* __restrict__ Hb,
                                                const float* __restrict__ bias,
                                                ushort* __restrict__ OUTb,
                                                uint32_t kk0, uint32_t kk1) {
    __shared__ ushort scol[GCAP];
    __shared__ uint32_t srow[65];
    int fp = blockIdx.x & 3;
    int c = blockIdx.x >> 2;
    int tid = threadIdx.x;
    int nbase = c * 64;
    int nend = nbase + 64; if (nend > N_NODES) nend = N_NODES;
    int nloc = nend - nbase;
    for (int i = tid; i <= nloc; i += 256) srow[i] = row[nbase + i];
    __syncthreads();
    uint32_t eLo = srow[0];
    uint32_t count = srow[nloc] - eLo;
    bool staged = count <= GCAP;
    if (staged) {
        for (uint32_t i = tid; i < count; i += 256) scol[i] = col16[eLo + i];
    }
    __syncthreads();

    int nl = tid >> 2;                 // node in block
    int q  = tid & 3;                  // 8-feat quarter of the 32-feat pair
    int v = nbase + nl;
    if (v >= N_NODES) return;
    const ushort* Hf = Hb + (size_t)fp * N_NODES * 32;
    ushort8_t hv = *((const ushort8_t*)(Hf + (size_t)v * 32 + q * 8));
    float acc[8];
    #pragma unroll
    for (int j = 0; j < 8; ++j) acc[j] = bf2f(hv[j]);

    uint32_t e0 = srow[nl] - eLo, e1 = srow[nl + 1] - eLo;
    uint32_t e = e0;
    if (staged) {
        for (; e + 4 <= e1; e += 4) {
            uint32_t s0 = scol[e], s1 = scol[e + 1], s2 = scol[e + 2], s3 = scol[e + 3];
            ushort8_t h0 = *((const ushort8_t*)(Hf + (size_t)s0 * 32 + q * 8));
            ushort8_t h1 = *((const ushort8_t*)(Hf + (size_t)s1 * 32 + q * 8));
            ushort8_t h2 = *((const ushort8_t*)(Hf + (size_t)s2 * 32 + q * 8));
            ushort8_t h3 = *((const ushort8_t*)(Hf + (size_t)s3 * 32 + q * 8));
            #pragma unroll
            for (int j = 0; j < 8; ++j)
                acc[j] += (bf2f(h0[j]) + bf2f(h1[j])) + (bf2f(h2[j]) + bf2f(h3[j]));
        }
        for (; e < e1; ++e) {
            uint32_t s0 = scol[e];
            ushort8_t h0 = *((const ushort8_t*)(Hf + (size_t)s0 * 32 + q * 8));
            #pragma unroll
            for (int j = 0; j < 8; ++j) acc[j] += bf2f(h0[j]);
        }
    } else {
        for (; e < e1; ++e) {
            uint32_t s0 = col16[eLo + e];
            ushort8_t h0 = *((const ushort8_t*)(Hf + (size_t)s0 * 32 + q * 8));
            #pragma unroll
            for (int j = 0; j < 8; ++j) acc[j] += bf2f(h0[j]);
        }
    }

    float dv = dis[v];
    int cbase = fp * 32 + q * 8;
    uint32_t ibase = (uint32_t)(v * DIM + cbase);
    ushort8_t o;
    #pragma unroll
    for (int j = 0; j < 8; ++j) {
        float z = acc[j] * dv + bias[cbase + j];
        z = (z >= 0.f) ? z : 0.01f * z;
        z *= drop_scale(kk0, kk1, ibase + j);
        o[j] = f2bf_rne(z);
    }
    *((ushort8_t*)(OUTb + (size_t)v * DIM + cbase)) = o;
}

// ---------------- MFMA GEMM launcher ----------------
__global__ __launch_bounds__(256) void k_gemm_mfma(const ushort* __restrict__ Xb,
                                                   const ushort* __restrict__ Wt,
                                                   const float* __restrict__ dis,
                                                   ushort* __restrict__ Hb) {
    gemm_body(Xb, Wt, dis, Hb, blockIdx.x, threadIdx.x);
}

// ---------------- classifier GEMM: (N x 128 bf16) @ (128 x 2 fp32), scaled ----
__global__ void k_gemm_cls(const ushort* __restrict__ Bb, const float* __restrict__ W3,
                           const float* __restrict__ dis, float* __restrict__ O) {
    int v = blockIdx.x * blockDim.x + threadIdx.x;
    if (v >= N_NODES) return;
    const uint32_t* r = (const uint32_t*)(Bb + (size_t)v * DIM);
    float a0 = 0.f, a1 = 0.f;
#pragma unroll 8
    for (int w = 0; w < 64; ++w) {
        uint32_t u = r[w];
        float x0 = bfpair_lo(u), x1 = bfpair_hi(u);
        const float* wp = W3 + w * 4;
        a0 += x0 * wp[0] + x1 * wp[2];
        a1 += x0 * wp[1] + x1 * wp[3];
    }
    float dv = dis[v];
    O[v * 2 + 0] = a0 * dv;
    O[v * 2 + 1] = a1 * dv;
}

// ---------------- fused layer-3 gather + bias + log_softmax, LDS-staged ------
__global__ __launch_bounds__(256) void k_gather3(const uint32_t* __restrict__ row,
                                                 const ushort* __restrict__ col16,
                                                 const float* __restrict__ dis,
                                                 const float* __restrict__ H3s,
                                                 const float* __restrict__ b3,
                                                 float* __restrict__ out) {
    __shared__ ushort scol[G3CAP];
    __shared__ uint32_t srow[257];
    int tid = threadIdx.x;
    int nbase = blockIdx.x * 256;
    int nend = nbase + 256; if (nend > N_NODES) nend = N_NODES;
    int nloc = nend - nbase;
    for (int i = tid; i <= nloc; i += 256) srow[i] = row[nbase + i];
    __syncthreads();
    uint32_t eLo = srow[0];
    uint32_t count = srow[nloc] - eLo;
    bool staged = count <= G3CAP;
    if (staged) {
        for (uint32_t i = tid; i < count; i += 256) scol[i] = col16[eLo + i];
    }
    __syncthreads();

    int v = nbase + tid;
    if (v >= N_NODES) return;
    const float2* H2 = (const float2*)H3s;
    float2 h = H2[v];
    float z0 = h.x, z1 = h.y;
    uint32_t e0 = srow[tid] - eLo, e1 = srow[tid + 1] - eLo;
    uint32_t e = e0;
    if (staged) {
        for (; e + 2 <= e1; e += 2) {
            float2 ha = H2[scol[e]];
            float2 hb = H2[scol[e + 1]];
            z0 += ha.x + hb.x; z1 += ha.y + hb.y;
        }
        if (e < e1) {
            float2 ha = H2[scol[e]];
            z0 += ha.x; z1 += ha.y;
        }
    } else {
        for (; e < e1; ++e) {
            float2 ha = H2[col16[eLo + e]];
            z0 += ha.x; z1 += ha.y;
        }
    }
    float dv = dis[v];
    z0 = z0 * dv + b3[0];
    z1 = z1 * dv + b3[1];
    float m = fmaxf(z0, z1);
    float lse = m + logf(expf(z0 - m) + expf(z1 - m));
    out[v * 2 + 0] = z0 - lse;
    out[v * 2 + 1] = z1 - lse;
}

extern "C" void kernel_launch(void* const* d_in, const int* in_sizes, int n_in,
                              void* d_out, int out_size, void* d_ws, size_t ws_size,
                              hipStream_t stream) {
    const float* x  = (const float*)d_in[0];
    const int*   ei = (const int*)d_in[1];
    const float* W1 = (const float*)d_in[2];
    const float* b1 = (const float*)d_in[3];
    const float* W2 = (const float*)d_in[4];
    const float* b2 = (const float*)d_in[5];
    const float* W3 = (const float*)d_in[6];
    const float* b3 = (const float*)d_in[7];
    float* out = (float*)d_out;

    const int* src = ei;
    const int* dst = ei + N_EDGES;

    // workspace layout (u32 units) -- all regions disjoint (R10 lesson)
    uint32_t* wsu = (uint32_t*)d_ws;
    float*    wsf = (float*)d_ws;
    uint32_t* gcur   = wsu;                       // [0, 196) -> pad 256
    uint32_t* row    = wsu + 256;                 // [256, 50257) -> pad 50304
    float*    dis    = wsf + 50304;               // [50304, 100304) -> pad 100352
    uint32_t* packed = wsu + 100352;              // 196*8192 -> [100352, 1705984)
    ushort*   col16  = (ushort*)(wsu + 1705984);  // 800000 u16 -> pad to 2106112
    ushort*   Hb     = (ushort*)(wsu + 2106112);  // [2106112, 5306112)
    ushort*   Xb     = (ushort*)(wsu + 5306112);  // [5306112, 8506112)
    ushort*   Bb     = (ushort*)(wsu + 8506112);  // [8506112, 11706112)
    ushort*   W1t    = (ushort*)(wsu + 11706112); // [11706112, 11714304)
    ushort*   W2t    = (ushort*)(wsu + 11714304); // [11714304, 11722496)
    float*    h3s    = wsf + 11722496;            // [11722496, 11822496)

    // dropout keys: threefry-partitionable fold-like split of key(42) (verified R0)
    uint32_t k1a, k1b, k2a, k2b;
    threefry2x32(0u, 42u, 0u, 0u, k1a, k1b);
    threefry2x32(0u, 42u, 0u, 1u, k2a, k2b);

    hipMemsetAsync(gcur, 0, 256 * sizeof(uint32_t), stream);

    // ---- A: converts | scatter (hist + reserve), 391 scatter blocks ----
    k_prep<<<XBLKS + 128 + NBLK, 256, 0, stream>>>(x, W1, W2, Xb, W1t, W2t,
                                                   src, dst, gcur, packed);

    // ---- CSR fill (compact; writes row/dis/col16) ----
    k_fill<<<NB, 256, 0, stream>>>(gcur, packed, row, dis, col16);

    int mgrid = (N_NODES + 127) / 128;                   // 391
    int ggrid = ((N_NODES + 63) / 64) * 4;               // (fp, 64-node chunk)

    // ---- layer 1 ----
    k_gemm_mfma<<<mgrid, 256, 0, stream>>>(Xb, W1t, dis, Hb);
    k_gather<<<ggrid, 256, 0, stream>>>(row, col16, dis, Hb, b1, Bb, k1a, k1b);

    // ---- layer 2 ----
    k_gemm_mfma<<<mgrid, 256, 0, stream>>>(Bb, W2t, dis, Hb);
    k_gather<<<ggrid, 256, 0, stream>>>(row, col16, dis, Hb, b2, Bb, k2a, k2b);

    // ---- layer 3 ----
    k_gemm_cls<<<(N_NODES + 255) / 256, 256, 0, stream>>>(Bb, W3, dis, h3s);
    k_gather3<<<(N_NODES + 255) / 256, 256, 0, stream>>>(row, col16, dis, h3s, b3, out);
}

// Round 19
// 231.115 us; speedup vs baseline: 1.3181x; 1.0449x over previous
//
#include <hip/hip_runtime.h>
#include <stdint.h>

#define N_NODES 50000
#define N_EDGES 800000
#define DIM     128
#define TOT     (N_NODES * DIM)   // 6,400,000
#define NB   196                 // dst buckets: dst>>8
#define CAP  8192                // fixed slots per bucket in 'packed' (mean 4096, sigma 64)
#define CHUNK 2048               // edges per scatter block (391 blocks)
#define NBLK 391                 // ceil(800000/2048)
#define GCAP 4096                // LDS edge cap for gather blocks (mean 1024 @64 nodes)
#define G3CAP 8192               // LDS edge cap for gather3 blocks (mean 4096)
#define XBLKS (TOT / 4 / 256)    // 6250

typedef __attribute__((ext_vector_type(8))) unsigned short ushort8_t;
typedef __attribute__((ext_vector_type(8))) short bfrag;    // 8 bf16 = 4 VGPR
typedef __attribute__((ext_vector_type(4))) float f32x4;

// ---------------- Threefry-2x32 (exact JAX 20-round) ----------------
__host__ __device__ inline void threefry2x32(uint32_t k0, uint32_t k1,
                                             uint32_t x0, uint32_t x1,
                                             uint32_t& o0, uint32_t& o1) {
    uint32_t ks0 = k0, ks1 = k1, ks2 = k0 ^ k1 ^ 0x1BD11BDAu;
    uint32_t v0 = x0 + ks0, v1 = x1 + ks1;
#define TF_R(r) { v0 += v1; v1 = (v1 << (r)) | (v1 >> (32 - (r))); v1 ^= v0; }
    TF_R(13) TF_R(15) TF_R(26) TF_R(6)
    v0 += ks1; v1 += ks2 + 1u;
    TF_R(17) TF_R(29) TF_R(16) TF_R(24)
    v0 += ks2; v1 += ks0 + 2u;
    TF_R(13) TF_R(15) TF_R(26) TF_R(6)
    v0 += ks0; v1 += ks1 + 3u;
    TF_R(17) TF_R(29) TF_R(16) TF_R(24)
    v0 += ks1; v1 += ks2 + 4u;
    TF_R(13) TF_R(15) TF_R(26) TF_R(6)
    v0 += ks2; v1 += ks0 + 5u;
#undef TF_R
    o0 = v0; o1 = v1;
}

__device__ inline float drop_scale(uint32_t kk0, uint32_t kk1, uint32_t i) {
    uint32_t b0, b1;
    threefry2x32(kk0, kk1, 0u, i, b0, b1);
    uint32_t bits = b0 ^ b1;               // partitionable 32-bit path (verified R0)
    return (bits >> 31) ? 0.0f : 2.0f;     // keep iff u < 0.5 iff top bit 0
}

__device__ inline float bf2f(ushort u) {
    return __uint_as_float(((uint32_t)u) << 16);
}
__device__ inline float bfpair_lo(uint32_t u) { return __uint_as_float(u << 16); }
__device__ inline float bfpair_hi(uint32_t u) { return __uint_as_float(u & 0xffff0000u); }

__device__ inline ushort f2bf_rne(float f) {
    uint32_t bits = __float_as_uint(f);
    uint32_t lsb = (bits >> 16) & 1u;
    bits += 0x7fffu + lsb;                 // round-to-nearest-even
    return (ushort)(bits >> 16);
}

// ---------------- MFMA GEMM body: H = X @ W, scaled bf16, 32-feat-pair out ---
// Hb[fp][v][32], fp in [0,4). [m89/m91 verified mapping; passed R11-R18]
__device__ inline void gemm_body(const ushort* __restrict__ Xb,
                                 const ushort* __restrict__ Wt,
                                 const float* __restrict__ dis,
                                 ushort* __restrict__ Hb, int gb, int tid) {
    int w = tid >> 6, lane = tid & 63;
    int m0 = gb * 128 + w * 32;
    int lrow = lane & 15, quad = lane >> 4;
    f32x4 acc[2][8] = {};
    for (int kt = 0; kt < DIM; kt += 32) {
        bfrag a[2], b[8];
        #pragma unroll
        for (int t = 0; t < 2; ++t) {
            int m = m0 + t * 16 + lrow;
            if (m >= N_NODES) m = 0;
            a[t] = *(const bfrag*)(Xb + (size_t)m * DIM + kt + quad * 8);
        }
        #pragma unroll
        for (int c = 0; c < 8; ++c) {
            int n = c * 16 + lrow;
            b[c] = *(const bfrag*)(Wt + (size_t)n * DIM + kt + quad * 8);
        }
        #pragma unroll
        for (int t = 0; t < 2; ++t)
            #pragma unroll
            for (int c = 0; c < 8; ++c)
                acc[t][c] = __builtin_amdgcn_mfma_f32_16x16x32_bf16(a[t], b[c], acc[t][c], 0, 0, 0);
    }
    #pragma unroll
    for (int t = 0; t < 2; ++t) {
        #pragma unroll
        for (int r = 0; r < 4; ++r) {
            int rowi = m0 + t * 16 + quad * 4 + r;
            if (rowi < N_NODES) {
                float dv = dis[rowi];
                #pragma unroll
                for (int c = 0; c < 8; ++c) {
                    int feat = c * 16 + lrow;
                    int fp = feat >> 5, off = feat & 31;
                    Hb[((size_t)fp * N_NODES + rowi) * 32 + off] = f2bf_rne(acc[t][c][r] * dv);
                }
            }
        }
    }
}

// ---- launch A: scatter FIRST (R18 lesson: latency-bound blocks must start at
// t=0 so their tail hides under the convert stream), then W transpose, then
// x->bf16 converts.
__global__ __launch_bounds__(256) void k_prep(const float* __restrict__ x,
                                              const float* __restrict__ W1,
                                              const float* __restrict__ W2,
                                              ushort* __restrict__ Xb,
                                              ushort* __restrict__ W1t,
                                              ushort* __restrict__ W2t,
                                              const int* __restrict__ src,
                                              const int* __restrict__ dst,
                                              uint32_t* __restrict__ gcur,
                                              uint32_t* __restrict__ packed) {
    __shared__ uint32_t h[NB];
    int b = blockIdx.x;
    int t = threadIdx.x;
    if (b < NBLK) {
        int sb = b;                                // scatter blocks start immediately
        if (t < NB) h[t] = 0u;
        __syncthreads();
        int base = sb * CHUNK;
        #pragma unroll
        for (int i = 0; i < CHUNK / 256; ++i) {
            int e = base + i * 256 + t;
            if (e < N_EDGES) atomicAdd(&h[((uint32_t)dst[e]) >> 8], 1u);
        }
        __syncthreads();
        if (t < NB) {
            uint32_t c = h[t];
            h[t] = c ? atomicAdd(&gcur[t], c) : 0u;   // reserve contiguous run
        }
        __syncthreads();
        #pragma unroll
        for (int i = 0; i < CHUNK / 256; ++i) {
            int e = base + i * 256 + t;
            if (e < N_EDGES) {
                uint32_t d = (uint32_t)dst[e];
                uint32_t s = (uint32_t)src[e];
                uint32_t bk = d >> 8;
                uint32_t pos = atomicAdd(&h[bk], 1u);
                if (pos < CAP)
                    packed[(size_t)bk * CAP + pos] = ((d & 255u) << 16) | s;
            }
        }
    } else if (b < NBLK + 128) {
        int j = (b - NBLK) * 256 + t;              // 0..32767
        const float* W = (j < DIM * DIM) ? W1 : W2;
        ushort* Wt = (j < DIM * DIM) ? W1t : W2t;
        int i = j & (DIM * DIM - 1);
        int k = i >> 7, n = i & 127;
        Wt[n * DIM + k] = f2bf_rne(W[k * DIM + n]);
    } else {
        int i = (b - NBLK - 128) * 256 + t;
        float4 v = ((const float4*)x)[i];
        ushort4 o;
        o.x = f2bf_rne(v.x); o.y = f2bf_rne(v.y);
        o.z = f2bf_rne(v.z); o.w = f2bf_rne(v.w);
        ((ushort4*)Xb)[i] = o;
    }
}

// ---- k_fill: per-bucket CSR -> COMPACT space; also writes row & dis ---------
// Compact base = LDS scan of gcur[0..b) (R16 pad-walk bug fix, verified R17/18).
__global__ __launch_bounds__(256) void k_fill(const uint32_t* __restrict__ gcur,
                                              const uint32_t* __restrict__ packed,
                                              uint32_t* __restrict__ row,
                                              float* __restrict__ dis,
                                              ushort* __restrict__ col16) {
    __shared__ uint32_t sdeg[256];
    __shared__ uint32_t scan[256];
    __shared__ uint32_t cur[256];
    int b = blockIdx.x;
    int t = threadIdx.x;
    uint32_t n = gcur[b];
    scan[t] = (t < b) ? gcur[t] : 0u;              // b <= 195 < 256
    __syncthreads();
    for (int off = 1; off < 256; off <<= 1) {
        uint32_t x = (t >= off) ? scan[t - off] : 0u;
        __syncthreads();
        scan[t] += x;
        __syncthreads();
    }
    uint32_t cbase = scan[255];
    __syncthreads();
    uint32_t pbase = (uint32_t)b * CAP;
    sdeg[t] = 0u;
    __syncthreads();
    uint32_t mine[24]; int cnt = 0;
    for (uint32_t i = t; i < n; i += 256) {
        uint32_t u = packed[pbase + i];
        mine[cnt++] = u;
        atomicAdd(&sdeg[u >> 16], 1u);
    }
    __syncthreads();
    uint32_t myd = sdeg[t];
    scan[t] = myd;
    __syncthreads();
    for (int off = 1; off < 256; off <<= 1) {
        uint32_t x = (t >= off) ? scan[t - off] : 0u;
        __syncthreads();
        scan[t] += x;
        __syncthreads();
    }
    uint32_t excl = scan[t] - myd;
    cur[t] = excl;
    int v = b * 256 + t;
    if (v <= N_NODES) row[v] = cbase + excl;       // compact; row[50000]=800000
    if (v < N_NODES)  dis[v] = 1.0f / sqrtf((float)(myd + 1u));
    __syncthreads();
    for (int j = 0; j < cnt; ++j) {
        uint32_t u = mine[j];
        uint32_t pos = cbase + atomicAdd(&cur[u >> 16], 1u);
        col16[pos] = (ushort)(u & 0xffffu);
    }
}

// ---------------- fused gather + bias + leaky + dropout ----------------
// Block (fp = blockIdx&3 -> 32-feat pair, c): 64 nodes; thread=(node, 8-feat q).
// 4 adjacent lanes read one 64B line per edge; line-complete 16B stores (R14).
__global__ __launch_bounds__(256) void k_gather(const uint32_t* __restrict__ row,
                                                const ushort* __restrict__ col16,
                                                const float* __restrict__ dis,
                                                const ushort* __restrict__ Hb,
                                                const float* __restrict__ bias,
                                                ushort* __restrict__ OUTb,
                                                uint32_t kk0, uint32_t kk1) {
    __shared__ ushort scol[GCAP];
    __shared__ uint32_t srow[65];
    int fp = blockIdx.x & 3;
    int c = blockIdx.x >> 2;
    int tid = threadIdx.x;
    int nbase = c * 64;
    int nend = nbase + 64; if (nend > N_NODES) nend = N_NODES;
    int nloc = nend - nbase;
    for (int i = tid; i <= nloc; i += 256) srow[i] = row[nbase + i];
    __syncthreads();
    uint32_t eLo = srow[0];
    uint32_t count = srow[nloc] - eLo;
    bool staged = count <= GCAP;
    if (staged) {
        for (uint32_t i = tid; i < count; i += 256) scol[i] = col16[eLo + i];
    }
    __syncthreads();

    int nl = tid >> 2;                 // node in block
    int q  = tid & 3;                  // 8-feat quarter of the 32-feat pair
    int v = nbase + nl;
    if (v >= N_NODES) return;
    const ushort* Hf = Hb + (size_t)fp * N_NODES * 32;
    ushort8_t hv = *((const ushort8_t*)(Hf + (size_t)v * 32 + q * 8));
    float acc[8];
    #pragma unroll
    for (int j = 0; j < 8; ++j) acc[j] = bf2f(hv[j]);

    uint32_t e0 = srow[nl] - eLo, e1 = srow[nl + 1] - eLo;
    uint32_t e = e0;
    if (staged) {
        for (; e + 4 <= e1; e += 4) {
            uint32_t s0 = scol[e], s1 = scol[e + 1], s2 = scol[e + 2], s3 = scol[e + 3];
            ushort8_t h0 = *((const ushort8_t*)(Hf + (size_t)s0 * 32 + q * 8));
            ushort8_t h1 = *((const ushort8_t*)(Hf + (size_t)s1 * 32 + q * 8));
            ushort8_t h2 = *((const ushort8_t*)(Hf + (size_t)s2 * 32 + q * 8));
            ushort8_t h3 = *((const ushort8_t*)(Hf + (size_t)s3 * 32 + q * 8));
            #pragma unroll
            for (int j = 0; j < 8; ++j)
                acc[j] += (bf2f(h0[j]) + bf2f(h1[j])) + (bf2f(h2[j]) + bf2f(h3[j]));
        }
        for (; e < e1; ++e) {
            uint32_t s0 = scol[e];
            ushort8_t h0 = *((const ushort8_t*)(Hf + (size_t)s0 * 32 + q * 8));
            #pragma unroll
            for (int j = 0; j < 8; ++j) acc[j] += bf2f(h0[j]);
        }
    } else {
        for (; e < e1; ++e) {
            uint32_t s0 = col16[eLo + e];
            ushort8_t h0 = *((const ushort8_t*)(Hf + (size_t)s0 * 32 + q * 8));
            #pragma unroll
            for (int j = 0; j < 8; ++j) acc[j] += bf2f(h0[j]);
        }
    }

    float dv = dis[v];
    int cbase = fp * 32 + q * 8;
    uint32_t ibase = (uint32_t)(v * DIM + cbase);
    ushort8_t o;
    #pragma unroll
    for (int j = 0; j < 8; ++j) {
        float z = acc[j] * dv + bias[cbase + j];
        z = (z >= 0.f) ? z : 0.01f * z;
        z *= drop_scale(kk0, kk1, ibase + j);
        o[j] = f2bf_rne(z);
    }
    *((ushort8_t*)(OUTb + (size_t)v * DIM + cbase)) = o;
}

// ---------------- MFMA GEMM launcher ----------------
__global__ __launch_bounds__(256) void k_gemm_mfma(const ushort* __restrict__ Xb,
                                                   const ushort* __restrict__ Wt,
                                                   const float* __restrict__ dis,
                                                   ushort* __restrict__ Hb) {
    gemm_body(Xb, Wt, dis, Hb, blockIdx.x, threadIdx.x);
}

// ---------------- classifier GEMM: (N x 128 bf16) @ (128 x 2 fp32), scaled ----
__global__ void k_gemm_cls(const ushort* __restrict__ Bb, const float* __restrict__ W3,
                           const float* __restrict__ dis, float* __restrict__ O) {
    int v = blockIdx.x * blockDim.x + threadIdx.x;
    if (v >= N_NODES) return;
    const uint32_t* r = (const uint32_t*)(Bb + (size_t)v * DIM);
    float a0 = 0.f, a1 = 0.f;
#pragma unroll 8
    for (int w = 0; w < 64; ++w) {
        uint32_t u = r[w];
        float x0 = bfpair_lo(u), x1 = bfpair_hi(u);
        const float* wp = W3 + w * 4;
        a0 += x0 * wp[0] + x1 * wp[2];
        a1 += x0 * wp[1] + x1 * wp[3];
    }
    float dv = dis[v];
    O[v * 2 + 0] = a0 * dv;
    O[v * 2 + 1] = a1 * dv;
}

// ---------------- fused layer-3 gather + bias + log_softmax, LDS-staged ------
__global__ __launch_bounds__(256) void k_gather3(const uint32_t* __restrict__ row,
                                                 const ushort* __restrict__ col16,
                                                 const float* __restrict__ dis,
                                                 const float* __restrict__ H3s,
                                                 const float* __restrict__ b3,
                                                 float* __restrict__ out) {
    __shared__ ushort scol[G3CAP];
    __shared__ uint32_t srow[257];
    int tid = threadIdx.x;
    int nbase = blockIdx.x * 256;
    int nend = nbase + 256; if (nend > N_NODES) nend = N_NODES;
    int nloc = nend - nbase;
    for (int i = tid; i <= nloc; i += 256) srow[i] = row[nbase + i];
    __syncthreads();
    uint32_t eLo = srow[0];
    uint32_t count = srow[nloc] - eLo;
    bool staged = count <= G3CAP;
    if (staged) {
        for (uint32_t i = tid; i < count; i += 256) scol[i] = col16[eLo + i];
    }
    __syncthreads();

    int v = nbase + tid;
    if (v >= N_NODES) return;
    const float2* H2 = (const float2*)H3s;
    float2 h = H2[v];
    float z0 = h.x, z1 = h.y;
    uint32_t e0 = srow[tid] - eLo, e1 = srow[tid + 1] - eLo;
    uint32_t e = e0;
    if (staged) {
        for (; e + 2 <= e1; e += 2) {
            float2 ha = H2[scol[e]];
            float2 hb = H2[scol[e + 1]];
            z0 += ha.x + hb.x; z1 += ha.y + hb.y;
        }
        if (e < e1) {
            float2 ha = H2[scol[e]];
            z0 += ha.x; z1 += ha.y;
        }
    } else {
        for (; e < e1; ++e) {
            float2 ha = H2[col16[eLo + e]];
            z0 += ha.x; z1 += ha.y;
        }
    }
    float dv = dis[v];
    z0 = z0 * dv + b3[0];
    z1 = z1 * dv + b3[1];
    float m = fmaxf(z0, z1);
    float lse = m + logf(expf(z0 - m) + expf(z1 - m));
    out[v * 2 + 0] = z0 - lse;
    out[v * 2 + 1] = z1 - lse;
}

extern "C" void kernel_launch(void* const* d_in, const int* in_sizes, int n_in,
                              void* d_out, int out_size, void* d_ws, size_t ws_size,
                              hipStream_t stream) {
    const float* x  = (const float*)d_in[0];
    const int*   ei = (const int*)d_in[1];
    const float* W1 = (const float*)d_in[2];
    const float* b1 = (const float*)d_in[3];
    const float* W2 = (const float*)d_in[4];
    const float* b2 = (const float*)d_in[5];
    const float* W3 = (const float*)d_in[6];
    const float* b3 = (const float*)d_in[7];
    float* out = (float*)d_out;

    const int* src = ei;
    const int* dst = ei + N_EDGES;

    // workspace layout (u32 units) -- all regions disjoint (R10 lesson)
    uint32_t* wsu = (uint32_t*)d_ws;
    float*    wsf = (float*)d_ws;
    uint32_t* gcur   = wsu;                       // [0, 196) -> pad 256
    uint32_t* row    = wsu + 256;                 // [256, 50257) -> pad 50304
    float*    dis    = wsf + 50304;               // [50304, 100304) -> pad 100352
    uint32_t* packed = wsu + 100352;              // 196*8192 -> [100352, 1705984)
    ushort*   col16  = (ushort*)(wsu + 1705984);  // 800000 u16 -> pad to 2106112
    ushort*   Hb     = (ushort*)(wsu + 2106112);  // [2106112, 5306112)
    ushort*   Xb     = (ushort*)(wsu + 5306112);  // [5306112, 8506112)
    ushort*   Bb     = (ushort*)(wsu + 8506112);  // [8506112, 11706112)
    ushort*   W1t    = (ushort*)(wsu + 11706112); // [11706112, 11714304)
    ushort*   W2t    = (ushort*)(wsu + 11714304); // [11714304, 11722496)
    float*    h3s    = wsf + 11722496;            // [11722496, 11822496)

    // dropout keys: threefry-partitionable fold-like split of key(42) (verified R0)
    uint32_t k1a, k1b, k2a, k2b;
    threefry2x32(0u, 42u, 0u, 0u, k1a, k1b);
    threefry2x32(0u, 42u, 0u, 1u, k2a, k2b);

    hipMemsetAsync(gcur, 0, 256 * sizeof(uint32_t), stream);

    // ---- A: scatter (first!) | W transpose | converts ----
    k_prep<<<NBLK + 128 + XBLKS, 256, 0, stream>>>(x, W1, W2, Xb, W1t, W2t,
                                                   src, dst, gcur, packed);

    // ---- CSR fill (compact; writes row/dis/col16) ----
    k_fill<<<NB, 256, 0, stream>>>(gcur, packed, row, dis, col16);

    int mgrid = (N_NODES + 127) / 128;                   // 391
    int ggrid = ((N_NODES + 63) / 64) * 4;               // (fp, 64-node chunk)

    // ---- layer 1 ----
    k_gemm_mfma<<<mgrid, 256, 0, stream>>>(Xb, W1t, dis, Hb);
    k_gather<<<ggrid, 256, 0, stream>>>(row, col16, dis, Hb, b1, Bb, k1a, k1b);

    // ---- layer 2 ----
    k_gemm_mfma<<<mgrid, 256, 0, stream>>>(Bb, W2t, dis, Hb);
    k_gather<<<ggrid, 256, 0, stream>>>(row, col16, dis, Hb, b2, Bb, k2a, k2b);

    // ---- layer 3 ----
    k_gemm_cls<<<(N_NODES + 255) / 256, 256, 0, stream>>>(Bb, W3, dis, h3s);
    k_gather3<<<(N_NODES + 255) / 256, 256, 0, stream>>>(row, col16, dis, h3s, b3, out);
}